// Round 2
// baseline (1227.312 us; speedup 1.0000x reference)
//
#include <hip/hip_runtime.h>
#include <math.h>

#define N_NODES 50000
#define N_EDGES 400000
#define H_HEADS 8
#define D_HEAD 16
#define R_TYPES 6
#define T_TYPES 4
#define DIM 128
#define BN 16                                      // nodes per GEMM tile
#define MAX_TILES ((N_NODES + BN - 1) / BN + T_TYPES)

// ======================= CSR build (group edges by dst) =======================

__global__ void k_count(const int* __restrict__ dst, int* __restrict__ deg, int n) {
    int e = blockIdx.x * blockDim.x + threadIdx.x;
    if (e < n) atomicAdd(&deg[dst[e]], 1);
}

__global__ void k_scanA(const int* __restrict__ deg, int* __restrict__ offs,
                        int* __restrict__ partial, int n) {
    __shared__ int tmp[256];
    int tid = threadIdx.x;
    int i = blockIdx.x * 256 + tid;
    int v = (i < n) ? deg[i] : 0;
    tmp[tid] = v;
    __syncthreads();
    for (int o = 1; o < 256; o <<= 1) {
        int t = (tid >= o) ? tmp[tid - o] : 0;
        __syncthreads();
        tmp[tid] += t;
        __syncthreads();
    }
    if (i < n) offs[i] = tmp[tid] - v;
    if (tid == 255) partial[blockIdx.x] = tmp[255];
}

__global__ void k_scanB(int* __restrict__ partial, int nb) {
    __shared__ int tmp[256];
    int tid = threadIdx.x;
    int v = (tid < nb) ? partial[tid] : 0;
    tmp[tid] = v;
    __syncthreads();
    for (int o = 1; o < 256; o <<= 1) {
        int t = (tid >= o) ? tmp[tid - o] : 0;
        __syncthreads();
        tmp[tid] += t;
        __syncthreads();
    }
    if (tid < nb) partial[tid] = tmp[tid] - v;
}

__global__ void k_scanC(int* __restrict__ offs, const int* __restrict__ partial, int n) {
    int i = blockIdx.x * 256 + threadIdx.x;
    if (i < n) offs[i] += partial[blockIdx.x];
}

__global__ void k_scatter(const int* __restrict__ dst, int* __restrict__ offs,
                          int* __restrict__ elist, int n) {
    int e = blockIdx.x * blockDim.x + threadIdx.x;
    if (e < n) {
        int pos = atomicAdd(&offs[dst[e]], 1);
        elist[pos] = e;
    }
}

// ======================= node type bucketing (padded 16-node tiles) ===========

__global__ void k_tcount(const int* __restrict__ ntype, int* __restrict__ tcnt, int n) {
    int i = blockIdx.x * 256 + threadIdx.x;
    if (i < n) atomicAdd(&tcnt[ntype[i]], 1);
}

__global__ void k_tsetup(const int* __restrict__ tcnt, int* __restrict__ pbase,
                         int* __restrict__ tcur, int* __restrict__ ntiles_g,
                         int* __restrict__ tile_type) {
    __shared__ int off[T_TYPES + 1];
    if (threadIdx.x == 0) {
        int o = 0;
        for (int t = 0; t < T_TYPES; ++t) {
            off[t] = o;
            pbase[t] = o * BN;
            tcur[t] = 0;
            o += (tcnt[t] + BN - 1) / BN;
        }
        off[T_TYPES] = o;
        *ntiles_g = o;
    }
    __syncthreads();
    int total = off[T_TYPES];
    for (int i = threadIdx.x; i < total; i += blockDim.x) {
        int t = 0;
        while (t < T_TYPES - 1 && i >= off[t + 1]) ++t;
        tile_type[i] = t;
    }
}

__global__ void k_tscatter(const int* __restrict__ ntype, int* __restrict__ tcur,
                           const int* __restrict__ pbase, int* __restrict__ nlist, int n) {
    int i = blockIdx.x * 256 + threadIdx.x;
    if (i < n) {
        int t = ntype[i];
        int p = atomicAdd(&tcur[t], 1);
        nlist[pbase[t] + p] = i;
    }
}

// ======================= K1: tiled typed-linear k,q,v =======================
// block = one 16-node type-uniform tile; 384 threads = (mat 0..2) x (col 0..127).
// x rows staged in LDS (pure broadcast reads); each thread reads ONE weight
// element per K-step -> weights fetched once per 16 nodes (16x L2 traffic cut).

__global__ __launch_bounds__(384) void k_kqv_gemm(
    const float* __restrict__ x, const int* __restrict__ nlist,
    const int* __restrict__ tile_type, const int* __restrict__ ntiles_g,
    const float* __restrict__ Wk, const float* __restrict__ Wq,
    const float* __restrict__ Wv,
    float* __restrict__ kb, float* __restrict__ qb, float* __restrict__ vb) {
    __shared__ float xs[BN][DIM];
    __shared__ int sids[BN];
    int b = blockIdx.x;
    if (b >= *ntiles_g) return;
    int tid = threadIdx.x;
    if (tid < BN) sids[tid] = nlist[b * BN + tid];
    __syncthreads();
    for (int idx = tid; idx < BN * DIM; idx += 384) {
        int row = idx >> 7, col = idx & 127;
        int nid = sids[row];
        xs[row][col] = (nid >= 0) ? x[(size_t)nid * DIM + col] : 0.f;
    }
    __syncthreads();
    int t = tile_type[b];
    int mat = tid >> 7;          // 0=k 1=q 2=v
    int col = tid & 127;
    const float* W = (mat == 0 ? Wk : (mat == 1 ? Wq : Wv)) + (size_t)t * DIM * DIM;
    float acc[BN];
#pragma unroll
    for (int n = 0; n < BN; ++n) acc[n] = 0.f;
#pragma unroll 4
    for (int d = 0; d < DIM; ++d) {
        float w = W[d * DIM + col];
#pragma unroll
        for (int n = 0; n < BN; ++n) acc[n] = fmaf(xs[n][d], w, acc[n]);
    }
    float* ob = (mat == 0 ? kb : (mat == 1 ? qb : vb));
    for (int n = 0; n < BN; ++n) {
        int nid = sids[n];
        if (nid >= 0) ob[(size_t)nid * DIM + col] = acc[n];
    }
}

// ======================= K2: per-edge attention logits =======================

__global__ void k_edge_a(const float* __restrict__ kbuf, const float* __restrict__ qbuf,
                         const int* __restrict__ src, const int* __restrict__ dst,
                         const int* __restrict__ etype,
                         const float* __restrict__ rel_att, const float* __restrict__ rel_pri,
                         float* __restrict__ a_ws, int nE) {
    __shared__ float A_l[256 * 48];   // 48 KB, layout [d*16+j][h*6+r]
    for (int idx = threadIdx.x; idx < H_HEADS * R_TYPES * 256; idx += 256) {
        int hr = idx >> 8;
        int dj = idx & 255;
        A_l[dj * 48 + hr] = rel_att[idx];
    }
    __syncthreads();
    int gid = blockIdx.x * 256 + threadIdx.x;
    int e = gid >> 3;
    int h = gid & 7;
    if (e >= nE) return;
    int s = src[e], dn = dst[e], r = etype[e];
    float kreg[D_HEAD], qreg[D_HEAD];
    const float* kp = kbuf + (size_t)s * DIM + h * D_HEAD;
    const float* qp = qbuf + (size_t)dn * DIM + h * D_HEAD;
#pragma unroll
    for (int d = 0; d < D_HEAD; ++d) { kreg[d] = kp[d]; qreg[d] = qp[d]; }
    int hr = h * R_TYPES + r;
    float acc = 0.f;
#pragma unroll
    for (int j = 0; j < D_HEAD; ++j) {
        float t = 0.f;
#pragma unroll
        for (int d = 0; d < D_HEAD; ++d)
            t = fmaf(kreg[d], A_l[(d * 16 + j) * 48 + hr], t);
        acc = fmaf(t, qreg[j], acc);
    }
    a_ws[(size_t)e * H_HEADS + h] = acc * rel_pri[h * R_TYPES + r] * 0.25f;
}

// ======================= K3: per-node softmax + aggregation ===================

__global__ void k_aggregate(const float* __restrict__ vbuf, const float* __restrict__ a_ws,
                            const int* __restrict__ offs_end, const int* __restrict__ deg,
                            const int* __restrict__ elist, const int* __restrict__ src,
                            const int* __restrict__ etype,
                            const float* __restrict__ rel_msg,
                            float* __restrict__ hacc, int n) {
    __shared__ float wsum[4][R_TYPES * 4 * 16];
    int wid = threadIdx.x >> 6;
    int lane = threadIdx.x & 63;
    int node = blockIdx.x * 4 + wid;
    bool valid = node < n;
    int g = lane >> 4;
    int d = lane & 15;
    int end = valid ? offs_end[node] : 0;
    int dg  = valid ? deg[node] : 0;
    int start = end - dg;
    float* ws_w = wsum[wid];

    for (int ho = 0; ho < 2; ++ho) {
        int h = ho * 4 + g;
        for (int r = 0; r < R_TYPES; ++r) ws_w[r * 64 + g * 16 + d] = 0.f;
        float m = -1e30f;
        for (int p = start; p < end; ++p) {
            int e = elist[p];
            m = fmaxf(m, a_ws[(size_t)e * H_HEADS + h]);
        }
        float den = 0.f;
        for (int p = start; p < end; ++p) {
            int e = elist[p];
            float ex = __expf(a_ws[(size_t)e * H_HEADS + h] - m);
            den += ex;
            int s = src[e], r = etype[e];
            float vv = vbuf[(size_t)s * DIM + h * D_HEAD + d];
            ws_w[r * 64 + g * 16 + d] += ex * vv;
        }
        __syncthreads();
        float acc = 0.f;
        for (int r = 0; r < R_TYPES; ++r) {
            const float* M = rel_msg + ((size_t)h * R_TYPES + r) * 256;
#pragma unroll
            for (int dp = 0; dp < 16; ++dp)
                acc = fmaf(ws_w[r * 64 + g * 16 + dp], M[dp * 16 + d], acc);
        }
        if (valid)
            hacc[(size_t)node * DIM + h * D_HEAD + d] = acc / fmaxf(den, 1e-9f);
        __syncthreads();
    }
}

// ======================= K4: tiled Wa + gate + residual + LayerNorm ===========
// block = one 16-node type-uniform tile; 256 threads = (half 0..1) x (col 0..127);
// each thread computes 8 nodes' col. Skip gate is uniform per tile.

__global__ __launch_bounds__(256) void k_final_gemm(
    const float* __restrict__ x, const int* __restrict__ nlist,
    const int* __restrict__ tile_type, const int* __restrict__ ntiles_g,
    const float* __restrict__ Wa, const float* __restrict__ skip,
    const float* __restrict__ gamma, const float* __restrict__ beta,
    float* __restrict__ out) {
    __shared__ float hs[BN][DIM];
    __shared__ float ys[BN][DIM];
    __shared__ int sids[BN];
    __shared__ float mred[BN], ired[BN];
    int b = blockIdx.x;
    if (b >= *ntiles_g) return;
    int tid = threadIdx.x;
    if (tid < BN) sids[tid] = nlist[b * BN + tid];
    __syncthreads();
    for (int idx = tid; idx < BN * DIM; idx += 256) {
        int row = idx >> 7, col = idx & 127;
        int nid = sids[row];
        hs[row][col] = (nid >= 0) ? out[(size_t)nid * DIM + col] : 0.f;
    }
    __syncthreads();
    int t = tile_type[b];
    int half = tid >> 7, col = tid & 127;
    const float* W = Wa + (size_t)t * DIM * DIM;
    float acc[8];
#pragma unroll
    for (int n = 0; n < 8; ++n) acc[n] = 0.f;
#pragma unroll 4
    for (int d = 0; d < DIM; ++d) {
        float w = W[d * DIM + col];
#pragma unroll
        for (int n = 0; n < 8; ++n) acc[n] = fmaf(hs[half * 8 + n][d], w, acc[n]);
    }
    float gte = 1.f / (1.f + __expf(-skip[t]));
#pragma unroll
    for (int n = 0; n < 8; ++n) {
        int row = half * 8 + n;
        int nid = sids[row];
        float xv = (nid >= 0) ? x[(size_t)nid * DIM + col] : 0.f;
        ys[row][col] = xv * (2.f - gte) + acc[n] * gte;   // x + h*g + x*(1-g)
    }
    __syncthreads();
    // LayerNorm: 16 threads per node reduce 128 values
    int ng = tid >> 4, l16 = tid & 15;
    float s = 0.f, s2 = 0.f;
#pragma unroll
    for (int k2 = 0; k2 < 8; ++k2) {
        float yv = ys[ng][l16 + 16 * k2];
        s += yv; s2 += yv * yv;
    }
#pragma unroll
    for (int m = 1; m < 16; m <<= 1) {
        s  += __shfl_xor(s, m, 64);
        s2 += __shfl_xor(s2, m, 64);
    }
    if (l16 == 0) {
        float mu = s * (1.f / DIM);
        float var = s2 * (1.f / DIM) - mu * mu;
        mred[ng] = mu;
        ired[ng] = rsqrtf(var + 1e-5f);
    }
    __syncthreads();
    float gm = gamma[col], bt = beta[col];
#pragma unroll
    for (int n = 0; n < 8; ++n) {
        int row = half * 8 + n;
        int nid = sids[row];
        if (nid >= 0)
            out[(size_t)nid * DIM + col] = (ys[row][col] - mred[row]) * ired[row] * gm + bt;
    }
}

// ======================= launcher =======================

extern "C" void kernel_launch(void* const* d_in, const int* in_sizes, int n_in,
                              void* d_out, int out_size, void* d_ws, size_t ws_size,
                              hipStream_t stream) {
    const float* x       = (const float*)d_in[0];
    const int*   src     = (const int*)d_in[1];
    const int*   dst     = (const int*)d_in[2];
    const int*   ntype   = (const int*)d_in[3];
    const int*   etype   = (const int*)d_in[4];
    const float* Wk      = (const float*)d_in[5];
    const float* Wq      = (const float*)d_in[6];
    const float* Wv      = (const float*)d_in[7];
    const float* Wa      = (const float*)d_in[8];
    const float* rel_pri = (const float*)d_in[9];
    const float* rel_att = (const float*)d_in[10];
    const float* rel_msg = (const float*)d_in[11];
    const float* skip    = (const float*)d_in[12];
    const float* gamma   = (const float*)d_in[13];
    const float* beta    = (const float*)d_in[14];
    float* out = (float*)d_out;

    const int N = N_NODES, E = N_EDGES;

    // workspace layout
    char* ws = (char*)d_ws;
    float* kb   = (float*)ws;                          // N*128
    float* qb   = kb + (size_t)N * DIM;                // N*128
    float* vb   = qb + (size_t)N * DIM;                // N*128
    float* a_ws = vb + (size_t)N * DIM;                // E*8
    int* deg     = (int*)(a_ws + (size_t)E * H_HEADS); // N
    int* offs    = deg + N;                            // N
    int* elist   = offs + N;                           // E
    int* partial = elist + E;                          // 256
    int* tcnt    = partial + 256;                      // 4
    int* tcur    = tcnt + T_TYPES;                     // 4
    int* pbase   = tcur + T_TYPES;                     // 4
    int* ntiles  = pbase + T_TYPES;                    // 1
    int* tile_type = ntiles + 1;                       // MAX_TILES
    int* nlist   = tile_type + MAX_TILES;              // MAX_TILES*BN

    const int nbScan = (N + 255) / 256;

    // CSR build (edges by dst)
    hipMemsetAsync(deg, 0, (size_t)N * sizeof(int), stream);
    k_count<<<(E + 255) / 256, 256, 0, stream>>>(dst, deg, E);
    k_scanA<<<nbScan, 256, 0, stream>>>(deg, offs, partial, N);
    k_scanB<<<1, 256, 0, stream>>>(partial, nbScan);
    k_scanC<<<nbScan, 256, 0, stream>>>(offs, partial, N);
    k_scatter<<<(E + 255) / 256, 256, 0, stream>>>(dst, offs, elist, E);

    // node type buckets (padded 16-node tiles)
    hipMemsetAsync(tcnt, 0, T_TYPES * sizeof(int), stream);
    k_tcount<<<nbScan, 256, 0, stream>>>(ntype, tcnt, N);
    k_tsetup<<<1, 256, 0, stream>>>(tcnt, pbase, tcur, ntiles, tile_type);
    hipMemsetAsync(nlist, 0xFF, (size_t)MAX_TILES * BN * sizeof(int), stream);
    k_tscatter<<<nbScan, 256, 0, stream>>>(ntype, tcur, pbase, nlist, N);

    // projections (tiled per-type GEMM)
    k_kqv_gemm<<<MAX_TILES, 384, 0, stream>>>(
        x, nlist, tile_type, ntiles, Wk, Wq, Wv, kb, qb, vb);

    // edge logits
    k_edge_a<<<(E * H_HEADS + 255) / 256, 256, 0, stream>>>(
        kb, qb, src, dst, etype, rel_att, rel_pri, a_ws, E);

    // per-node softmax + message aggregation -> d_out (scratch)
    k_aggregate<<<(N + 3) / 4, 256, 0, stream>>>(
        vb, a_ws, offs, deg, elist, src, etype, rel_msg, out, N);

    // output projection + gate + residual + LayerNorm (tiled, in place on d_out)
    k_final_gemm<<<MAX_TILES, 256, 0, stream>>>(
        x, nlist, tile_type, ntiles, Wa, skip, gamma, beta, out);
}

// Round 3
// 649.988 us; speedup vs baseline: 1.8882x; 1.8882x over previous
//
#include <hip/hip_runtime.h>
#include <math.h>

#define N_NODES 50000
#define N_EDGES 400000
#define H_HEADS 8
#define D_HEAD 16
#define R_TYPES 6
#define T_TYPES 4
#define DIM 128
#define BN 16                                      // nodes per GEMM tile
#define MAX_TILES ((N_NODES + BN - 1) / BN + T_TYPES)

// ======================= CSR build (group edges by dst) =======================

__global__ void k_count(const int* __restrict__ dst, int* __restrict__ deg, int n) {
    int e = blockIdx.x * blockDim.x + threadIdx.x;
    if (e < n) atomicAdd(&deg[dst[e]], 1);
}

__global__ void k_scanA(const int* __restrict__ deg, int* __restrict__ offs,
                        int* __restrict__ partial, int n) {
    __shared__ int tmp[256];
    int tid = threadIdx.x;
    int i = blockIdx.x * 256 + tid;
    int v = (i < n) ? deg[i] : 0;
    tmp[tid] = v;
    __syncthreads();
    for (int o = 1; o < 256; o <<= 1) {
        int t = (tid >= o) ? tmp[tid - o] : 0;
        __syncthreads();
        tmp[tid] += t;
        __syncthreads();
    }
    if (i < n) offs[i] = tmp[tid] - v;
    if (tid == 255) partial[blockIdx.x] = tmp[255];
}

__global__ void k_scanB(int* __restrict__ partial, int nb) {
    __shared__ int tmp[256];
    int tid = threadIdx.x;
    int v = (tid < nb) ? partial[tid] : 0;
    tmp[tid] = v;
    __syncthreads();
    for (int o = 1; o < 256; o <<= 1) {
        int t = (tid >= o) ? tmp[tid - o] : 0;
        __syncthreads();
        tmp[tid] += t;
        __syncthreads();
    }
    if (tid < nb) partial[tid] = tmp[tid] - v;
}

__global__ void k_scanC(int* __restrict__ offs, const int* __restrict__ partial, int n) {
    int i = blockIdx.x * 256 + threadIdx.x;
    if (i < n) offs[i] += partial[blockIdx.x];
}

__global__ void k_scatter(const int* __restrict__ dst, int* __restrict__ offs,
                          int* __restrict__ elist, int n) {
    int e = blockIdx.x * blockDim.x + threadIdx.x;
    if (e < n) {
        int pos = atomicAdd(&offs[dst[e]], 1);
        elist[pos] = e;
    }
}

// ======================= node type bucketing (padded 16-node tiles) ===========
// Block-aggregated: LDS histogram -> 4 global atomics per block (was 1 per node).

__global__ void k_tcount_agg(const int* __restrict__ ntype, int* __restrict__ tcnt,
                             int* __restrict__ wpos, int n) {
    __shared__ int hist[T_TYPES];
    __shared__ int base[T_TYPES];
    int tid = threadIdx.x;
    if (tid < T_TYPES) hist[tid] = 0;
    __syncthreads();
    int i = blockIdx.x * 256 + tid;
    int t = 0, rank = 0;
    if (i < n) {
        t = ntype[i];
        rank = atomicAdd(&hist[t], 1);       // LDS atomic: within-block rank
    }
    __syncthreads();
    if (tid < T_TYPES)
        base[tid] = (hist[tid] > 0) ? atomicAdd(&tcnt[tid], hist[tid]) : 0;
    __syncthreads();
    if (i < n) wpos[i] = base[t] + rank;     // within-type position
}

__global__ void k_tsetup(const int* __restrict__ tcnt, int* __restrict__ pbase,
                         int* __restrict__ ntiles_g, int* __restrict__ tile_type) {
    __shared__ int off[T_TYPES + 1];
    if (threadIdx.x == 0) {
        int o = 0;
        for (int t = 0; t < T_TYPES; ++t) {
            off[t] = o;
            pbase[t] = o * BN;
            o += (tcnt[t] + BN - 1) / BN;
        }
        off[T_TYPES] = o;
        *ntiles_g = o;
    }
    __syncthreads();
    int total = off[T_TYPES];
    for (int i = threadIdx.x; i < total; i += blockDim.x) {
        int t = 0;
        while (t < T_TYPES - 1 && i >= off[t + 1]) ++t;
        tile_type[i] = t;
    }
}

__global__ void k_tscatter2(const int* __restrict__ ntype, const int* __restrict__ wpos,
                            const int* __restrict__ pbase, int* __restrict__ nlist, int n) {
    int i = blockIdx.x * 256 + threadIdx.x;
    if (i < n) nlist[pbase[ntype[i]] + wpos[i]] = i;   // no atomics
}

// ======================= K1: tiled typed-linear k,q,v =======================
// block = one 16-node type-uniform tile; 384 threads = (mat 0..2) x (col 0..127).

__global__ __launch_bounds__(384) void k_kqv_gemm(
    const float* __restrict__ x, const int* __restrict__ nlist,
    const int* __restrict__ tile_type, const int* __restrict__ ntiles_g,
    const float* __restrict__ Wk, const float* __restrict__ Wq,
    const float* __restrict__ Wv,
    float* __restrict__ kb, float* __restrict__ qb, float* __restrict__ vb) {
    __shared__ float xs[BN][DIM];
    __shared__ int sids[BN];
    int b = blockIdx.x;
    if (b >= *ntiles_g) return;
    int tid = threadIdx.x;
    if (tid < BN) sids[tid] = nlist[b * BN + tid];
    __syncthreads();
    for (int idx = tid; idx < BN * DIM; idx += 384) {
        int row = idx >> 7, col = idx & 127;
        int nid = sids[row];
        xs[row][col] = (nid >= 0) ? x[(size_t)nid * DIM + col] : 0.f;
    }
    __syncthreads();
    int t = tile_type[b];
    int mat = tid >> 7;          // 0=k 1=q 2=v
    int col = tid & 127;
    const float* W = (mat == 0 ? Wk : (mat == 1 ? Wq : Wv)) + (size_t)t * DIM * DIM;
    float acc[BN];
#pragma unroll
    for (int n = 0; n < BN; ++n) acc[n] = 0.f;
#pragma unroll 4
    for (int d = 0; d < DIM; ++d) {
        float w = W[d * DIM + col];
#pragma unroll
        for (int n = 0; n < BN; ++n) acc[n] = fmaf(xs[n][d], w, acc[n]);
    }
    float* ob = (mat == 0 ? kb : (mat == 1 ? qb : vb));
    for (int n = 0; n < BN; ++n) {
        int nid = sids[n];
        if (nid >= 0) ob[(size_t)nid * DIM + col] = acc[n];
    }
}

// ======================= K2: per-edge attention logits =======================

__global__ void k_edge_a(const float* __restrict__ kbuf, const float* __restrict__ qbuf,
                         const int* __restrict__ src, const int* __restrict__ dst,
                         const int* __restrict__ etype,
                         const float* __restrict__ rel_att, const float* __restrict__ rel_pri,
                         float* __restrict__ a_ws, int nE) {
    __shared__ float A_l[256 * 48];   // 48 KB, layout [d*16+j][h*6+r]
    for (int idx = threadIdx.x; idx < H_HEADS * R_TYPES * 256; idx += 256) {
        int hr = idx >> 8;
        int dj = idx & 255;
        A_l[dj * 48 + hr] = rel_att[idx];
    }
    __syncthreads();
    int gid = blockIdx.x * 256 + threadIdx.x;
    int e = gid >> 3;
    int h = gid & 7;
    if (e >= nE) return;
    int s = src[e], dn = dst[e], r = etype[e];
    float kreg[D_HEAD], qreg[D_HEAD];
    const float* kp = kbuf + (size_t)s * DIM + h * D_HEAD;
    const float* qp = qbuf + (size_t)dn * DIM + h * D_HEAD;
#pragma unroll
    for (int d = 0; d < D_HEAD; ++d) { kreg[d] = kp[d]; qreg[d] = qp[d]; }
    int hr = h * R_TYPES + r;
    float acc = 0.f;
#pragma unroll
    for (int j = 0; j < D_HEAD; ++j) {
        float t = 0.f;
#pragma unroll
        for (int d = 0; d < D_HEAD; ++d)
            t = fmaf(kreg[d], A_l[(d * 16 + j) * 48 + hr], t);
        acc = fmaf(t, qreg[j], acc);
    }
    a_ws[(size_t)e * H_HEADS + h] = acc * rel_pri[h * R_TYPES + r] * 0.25f;
}

// ======================= K3: per-node softmax + aggregation ===================

__global__ void k_aggregate(const float* __restrict__ vbuf, const float* __restrict__ a_ws,
                            const int* __restrict__ offs_end, const int* __restrict__ deg,
                            const int* __restrict__ elist, const int* __restrict__ src,
                            const int* __restrict__ etype,
                            const float* __restrict__ rel_msg,
                            float* __restrict__ hacc, int n) {
    __shared__ float wsum[4][R_TYPES * 4 * 16];
    int wid = threadIdx.x >> 6;
    int lane = threadIdx.x & 63;
    int node = blockIdx.x * 4 + wid;
    bool valid = node < n;
    int g = lane >> 4;
    int d = lane & 15;
    int end = valid ? offs_end[node] : 0;
    int dg  = valid ? deg[node] : 0;
    int start = end - dg;
    float* ws_w = wsum[wid];

    for (int ho = 0; ho < 2; ++ho) {
        int h = ho * 4 + g;
        for (int r = 0; r < R_TYPES; ++r) ws_w[r * 64 + g * 16 + d] = 0.f;
        float m = -1e30f;
        for (int p = start; p < end; ++p) {
            int e = elist[p];
            m = fmaxf(m, a_ws[(size_t)e * H_HEADS + h]);
        }
        float den = 0.f;
        for (int p = start; p < end; ++p) {
            int e = elist[p];
            float ex = __expf(a_ws[(size_t)e * H_HEADS + h] - m);
            den += ex;
            int s = src[e], r = etype[e];
            float vv = vbuf[(size_t)s * DIM + h * D_HEAD + d];
            ws_w[r * 64 + g * 16 + d] += ex * vv;
        }
        __syncthreads();
        float acc = 0.f;
        for (int r = 0; r < R_TYPES; ++r) {
            const float* M = rel_msg + ((size_t)h * R_TYPES + r) * 256;
#pragma unroll
            for (int dp = 0; dp < 16; ++dp)
                acc = fmaf(ws_w[r * 64 + g * 16 + dp], M[dp * 16 + d], acc);
        }
        if (valid)
            hacc[(size_t)node * DIM + h * D_HEAD + d] = acc / fmaxf(den, 1e-9f);
        __syncthreads();
    }
}

// ======================= K4: tiled Wa + gate + residual + LayerNorm ===========

__global__ __launch_bounds__(256) void k_final_gemm(
    const float* __restrict__ x, const int* __restrict__ nlist,
    const int* __restrict__ tile_type, const int* __restrict__ ntiles_g,
    const float* __restrict__ Wa, const float* __restrict__ skip,
    const float* __restrict__ gamma, const float* __restrict__ beta,
    float* __restrict__ out) {
    __shared__ float hs[BN][DIM];
    __shared__ float ys[BN][DIM];
    __shared__ int sids[BN];
    __shared__ float mred[BN], ired[BN];
    int b = blockIdx.x;
    if (b >= *ntiles_g) return;
    int tid = threadIdx.x;
    if (tid < BN) sids[tid] = nlist[b * BN + tid];
    __syncthreads();
    for (int idx = tid; idx < BN * DIM; idx += 256) {
        int row = idx >> 7, col = idx & 127;
        int nid = sids[row];
        hs[row][col] = (nid >= 0) ? out[(size_t)nid * DIM + col] : 0.f;
    }
    __syncthreads();
    int t = tile_type[b];
    int half = tid >> 7, col = tid & 127;
    const float* W = Wa + (size_t)t * DIM * DIM;
    float acc[8];
#pragma unroll
    for (int n = 0; n < 8; ++n) acc[n] = 0.f;
#pragma unroll 4
    for (int d = 0; d < DIM; ++d) {
        float w = W[d * DIM + col];
#pragma unroll
        for (int n = 0; n < 8; ++n) acc[n] = fmaf(hs[half * 8 + n][d], w, acc[n]);
    }
    float gte = 1.f / (1.f + __expf(-skip[t]));
#pragma unroll
    for (int n = 0; n < 8; ++n) {
        int row = half * 8 + n;
        int nid = sids[row];
        float xv = (nid >= 0) ? x[(size_t)nid * DIM + col] : 0.f;
        ys[row][col] = xv * (2.f - gte) + acc[n] * gte;   // x + h*g + x*(1-g)
    }
    __syncthreads();
    // LayerNorm: 16 threads per node reduce 128 values
    int ng = tid >> 4, l16 = tid & 15;
    float s = 0.f, s2 = 0.f;
#pragma unroll
    for (int k2 = 0; k2 < 8; ++k2) {
        float yv = ys[ng][l16 + 16 * k2];
        s += yv; s2 += yv * yv;
    }
#pragma unroll
    for (int m = 1; m < 16; m <<= 1) {
        s  += __shfl_xor(s, m, 64);
        s2 += __shfl_xor(s2, m, 64);
    }
    if (l16 == 0) {
        float mu = s * (1.f / DIM);
        float var = s2 * (1.f / DIM) - mu * mu;
        mred[ng] = mu;
        ired[ng] = rsqrtf(var + 1e-5f);
    }
    __syncthreads();
    float gm = gamma[col], bt = beta[col];
#pragma unroll
    for (int n = 0; n < 8; ++n) {
        int row = half * 8 + n;
        int nid = sids[row];
        if (nid >= 0)
            out[(size_t)nid * DIM + col] = (ys[row][col] - mred[row]) * ired[row] * gm + bt;
    }
}

// ======================= launcher =======================

extern "C" void kernel_launch(void* const* d_in, const int* in_sizes, int n_in,
                              void* d_out, int out_size, void* d_ws, size_t ws_size,
                              hipStream_t stream) {
    const float* x       = (const float*)d_in[0];
    const int*   src     = (const int*)d_in[1];
    const int*   dst     = (const int*)d_in[2];
    const int*   ntype   = (const int*)d_in[3];
    const int*   etype   = (const int*)d_in[4];
    const float* Wk      = (const float*)d_in[5];
    const float* Wq      = (const float*)d_in[6];
    const float* Wv      = (const float*)d_in[7];
    const float* Wa      = (const float*)d_in[8];
    const float* rel_pri = (const float*)d_in[9];
    const float* rel_att = (const float*)d_in[10];
    const float* rel_msg = (const float*)d_in[11];
    const float* skip    = (const float*)d_in[12];
    const float* gamma   = (const float*)d_in[13];
    const float* beta    = (const float*)d_in[14];
    float* out = (float*)d_out;

    const int N = N_NODES, E = N_EDGES;

    // workspace layout
    char* ws = (char*)d_ws;
    float* kb   = (float*)ws;                          // N*128
    float* qb   = kb + (size_t)N * DIM;                // N*128
    float* vb   = qb + (size_t)N * DIM;                // N*128
    float* a_ws = vb + (size_t)N * DIM;                // E*8
    int* deg     = (int*)(a_ws + (size_t)E * H_HEADS); // N
    int* offs    = deg + N;                            // N
    int* elist   = offs + N;                           // E
    int* partial = elist + E;                          // 256
    int* tcnt    = partial + 256;                      // 4
    int* pbase   = tcnt + T_TYPES;                     // 4
    int* ntiles  = pbase + T_TYPES;                    // 1
    int* tile_type = ntiles + 1;                       // MAX_TILES
    int* nlist   = tile_type + MAX_TILES;              // MAX_TILES*BN
    int* wpos    = nlist + (size_t)MAX_TILES * BN;     // N

    const int nbScan = (N + 255) / 256;

    // CSR build (edges by dst)
    hipMemsetAsync(deg, 0, (size_t)N * sizeof(int), stream);
    k_count<<<(E + 255) / 256, 256, 0, stream>>>(dst, deg, E);
    k_scanA<<<nbScan, 256, 0, stream>>>(deg, offs, partial, N);
    k_scanB<<<1, 256, 0, stream>>>(partial, nbScan);
    k_scanC<<<nbScan, 256, 0, stream>>>(offs, partial, N);
    k_scatter<<<(E + 255) / 256, 256, 0, stream>>>(dst, offs, elist, E);

    // node type buckets (padded 16-node tiles) — block-aggregated atomics
    hipMemsetAsync(tcnt, 0, T_TYPES * sizeof(int), stream);
    k_tcount_agg<<<nbScan, 256, 0, stream>>>(ntype, tcnt, wpos, N);
    k_tsetup<<<1, 256, 0, stream>>>(tcnt, pbase, ntiles, tile_type);
    hipMemsetAsync(nlist, 0xFF, (size_t)MAX_TILES * BN * sizeof(int), stream);
    k_tscatter2<<<nbScan, 256, 0, stream>>>(ntype, wpos, pbase, nlist, N);

    // projections (tiled per-type GEMM)
    k_kqv_gemm<<<MAX_TILES, 384, 0, stream>>>(
        x, nlist, tile_type, ntiles, Wk, Wq, Wv, kb, qb, vb);

    // edge logits
    k_edge_a<<<(E * H_HEADS + 255) / 256, 256, 0, stream>>>(
        kb, qb, src, dst, etype, rel_att, rel_pri, a_ws, E);

    // per-node softmax + message aggregation -> d_out (scratch)
    k_aggregate<<<(N + 3) / 4, 256, 0, stream>>>(
        vb, a_ws, offs, deg, elist, src, etype, rel_msg, out, N);

    // output projection + gate + residual + LayerNorm (tiled, in place on d_out)
    k_final_gemm<<<MAX_TILES, 256, 0, stream>>>(
        x, nlist, tile_type, ntiles, Wa, skip, gamma, beta, out);
}

// Round 4
// 520.910 us; speedup vs baseline: 2.3561x; 1.2478x over previous
//
#include <hip/hip_runtime.h>
#include <math.h>

#define N_NODES 50000
#define N_EDGES 400000
#define H_HEADS 8
#define D_HEAD 16
#define R_TYPES 6
#define T_TYPES 4
#define DIM 128
#define BN 16                                      // nodes per GEMM tile
#define MAX_TILES ((N_NODES + BN - 1) / BN + T_TYPES)
#define NBLK_E ((N_EDGES + 255) / 256)             // 1563

// ======================= CSR build (group edges by dst) =======================

__global__ void k_count(const int* __restrict__ dst, int* __restrict__ deg, int n) {
    int e = blockIdx.x * blockDim.x + threadIdx.x;
    if (e < n) atomicAdd(&deg[dst[e]], 1);
}

__global__ void k_scanA(const int* __restrict__ deg, int* __restrict__ offs,
                        int* __restrict__ partial, int n) {
    __shared__ int tmp[256];
    int tid = threadIdx.x;
    int i = blockIdx.x * 256 + tid;
    int v = (i < n) ? deg[i] : 0;
    tmp[tid] = v;
    __syncthreads();
    for (int o = 1; o < 256; o <<= 1) {
        int t = (tid >= o) ? tmp[tid - o] : 0;
        __syncthreads();
        tmp[tid] += t;
        __syncthreads();
    }
    if (i < n) offs[i] = tmp[tid] - v;
    if (tid == 255) partial[blockIdx.x] = tmp[255];
}

__global__ void k_scanB(int* __restrict__ partial, int nb) {
    __shared__ int tmp[256];
    int tid = threadIdx.x;
    int v = (tid < nb) ? partial[tid] : 0;
    tmp[tid] = v;
    __syncthreads();
    for (int o = 1; o < 256; o <<= 1) {
        int t = (tid >= o) ? tmp[tid - o] : 0;
        __syncthreads();
        tmp[tid] += t;
        __syncthreads();
    }
    if (tid < nb) partial[tid] = tmp[tid] - v;
}

__global__ void k_scanC(int* __restrict__ offs, const int* __restrict__ partial, int n) {
    int i = blockIdx.x * 256 + threadIdx.x;
    if (i < n) offs[i] += partial[blockIdx.x];
}

// scatter edges into CSR order, materializing src/dst/etype at sorted position
__global__ void k_scatter2(const int* __restrict__ src, const int* __restrict__ dst,
                           const int* __restrict__ etype, int* __restrict__ offs,
                           int* __restrict__ esrc_s, int* __restrict__ edst_s,
                           int* __restrict__ ety_s, int n) {
    int e = blockIdx.x * blockDim.x + threadIdx.x;
    if (e < n) {
        int pos = atomicAdd(&offs[dst[e]], 1);   // offs becomes END offset
        esrc_s[pos] = src[e];
        edst_s[pos] = dst[e];
        ety_s[pos]  = etype[e];
    }
}

// ======================= r-sort of CSR positions (counting sort) ==============

__global__ void k_rhist(const int* __restrict__ ety_s, int* __restrict__ rcnt, int n) {
    __shared__ int h[R_TYPES];
    int tid = threadIdx.x;
    if (tid < R_TYPES) h[tid] = 0;
    __syncthreads();
    int i = blockIdx.x * 256 + tid;
    if (i < n) atomicAdd(&h[ety_s[i]], 1);
    __syncthreads();
    if (tid < R_TYPES) rcnt[tid * NBLK_E + blockIdx.x] = h[tid];
}

__global__ void k_rscan(int* __restrict__ a, int total) {
    __shared__ int tmp[256];
    __shared__ int carry_s;
    int tid = threadIdx.x;
    if (tid == 0) carry_s = 0;
    __syncthreads();
    for (int base = 0; base < total; base += 256) {
        int i = base + tid;
        int v = (i < total) ? a[i] : 0;
        tmp[tid] = v;
        __syncthreads();
        for (int o = 1; o < 256; o <<= 1) {
            int t = (tid >= o) ? tmp[tid - o] : 0;
            __syncthreads();
            tmp[tid] += t;
            __syncthreads();
        }
        int carry = carry_s;
        if (i < total) a[i] = carry + tmp[tid] - v;   // exclusive
        __syncthreads();
        if (tid == 255) carry_s = carry + tmp[255];
        __syncthreads();
    }
}

__global__ void k_rscatter(const int* __restrict__ esrc_s, const int* __restrict__ edst_s,
                           const int* __restrict__ ety_s, const int* __restrict__ rbase,
                           int* __restrict__ sp_src, int* __restrict__ sp_dst,
                           int* __restrict__ sp_r, int* __restrict__ sp_pos, int n) {
    __shared__ int hist[R_TYPES];
    __shared__ int base[R_TYPES];
    int tid = threadIdx.x;
    if (tid < R_TYPES) hist[tid] = 0;
    __syncthreads();
    int p = blockIdx.x * 256 + tid;
    int r = 0, rank = 0;
    if (p < n) {
        r = ety_s[p];
        rank = atomicAdd(&hist[r], 1);
    }
    __syncthreads();
    if (tid < R_TYPES) base[tid] = rbase[tid * NBLK_E + blockIdx.x];
    __syncthreads();
    if (p < n) {
        int q2 = base[r] + rank;
        sp_src[q2] = esrc_s[p];
        sp_dst[q2] = edst_s[p];
        sp_r[q2]   = r;
        sp_pos[q2] = p;
    }
}

// ======================= node type bucketing (padded 16-node tiles) ===========

__global__ void k_tcount_agg(const int* __restrict__ ntype, int* __restrict__ tcnt,
                             int* __restrict__ wpos, int n) {
    __shared__ int hist[T_TYPES];
    __shared__ int base[T_TYPES];
    int tid = threadIdx.x;
    if (tid < T_TYPES) hist[tid] = 0;
    __syncthreads();
    int i = blockIdx.x * 256 + tid;
    int t = 0, rank = 0;
    if (i < n) {
        t = ntype[i];
        rank = atomicAdd(&hist[t], 1);
    }
    __syncthreads();
    if (tid < T_TYPES)
        base[tid] = (hist[tid] > 0) ? atomicAdd(&tcnt[tid], hist[tid]) : 0;
    __syncthreads();
    if (i < n) wpos[i] = base[t] + rank;
}

__global__ void k_tsetup(const int* __restrict__ tcnt, int* __restrict__ pbase,
                         int* __restrict__ ntiles_g, int* __restrict__ tile_type) {
    __shared__ int off[T_TYPES + 1];
    if (threadIdx.x == 0) {
        int o = 0;
        for (int t = 0; t < T_TYPES; ++t) {
            off[t] = o;
            pbase[t] = o * BN;
            o += (tcnt[t] + BN - 1) / BN;
        }
        off[T_TYPES] = o;
        *ntiles_g = o;
    }
    __syncthreads();
    int total = off[T_TYPES];
    for (int i = threadIdx.x; i < total; i += blockDim.x) {
        int t = 0;
        while (t < T_TYPES - 1 && i >= off[t + 1]) ++t;
        tile_type[i] = t;
    }
}

__global__ void k_tscatter2(const int* __restrict__ ntype, const int* __restrict__ wpos,
                            const int* __restrict__ pbase, int* __restrict__ nlist, int n) {
    int i = blockIdx.x * 256 + threadIdx.x;
    if (i < n) nlist[pbase[ntype[i]] + wpos[i]] = i;
}

// ======================= K1: tiled typed-linear k,q,v =======================

__global__ __launch_bounds__(384) void k_kqv_gemm(
    const float* __restrict__ x, const int* __restrict__ nlist,
    const int* __restrict__ tile_type, const int* __restrict__ ntiles_g,
    const float* __restrict__ Wk, const float* __restrict__ Wq,
    const float* __restrict__ Wv,
    float* __restrict__ kb, float* __restrict__ qb, float* __restrict__ vb) {
    __shared__ float xs[BN][DIM];
    __shared__ int sids[BN];
    int b = blockIdx.x;
    if (b >= *ntiles_g) return;
    int tid = threadIdx.x;
    if (tid < BN) sids[tid] = nlist[b * BN + tid];
    __syncthreads();
    for (int idx = tid; idx < BN * DIM; idx += 384) {
        int row = idx >> 7, col = idx & 127;
        int nid = sids[row];
        xs[row][col] = (nid >= 0) ? x[(size_t)nid * DIM + col] : 0.f;
    }
    __syncthreads();
    int t = tile_type[b];
    int mat = tid >> 7;          // 0=k 1=q 2=v
    int col = tid & 127;
    const float* W = (mat == 0 ? Wk : (mat == 1 ? Wq : Wv)) + (size_t)t * DIM * DIM;
    float acc[BN];
#pragma unroll
    for (int n = 0; n < BN; ++n) acc[n] = 0.f;
#pragma unroll 4
    for (int d = 0; d < DIM; ++d) {
        float w = W[d * DIM + col];
#pragma unroll
        for (int n = 0; n < BN; ++n) acc[n] = fmaf(xs[n][d], w, acc[n]);
    }
    float* ob = (mat == 0 ? kb : (mat == 1 ? qb : vb));
    for (int n = 0; n < BN; ++n) {
        int nid = sids[n];
        if (nid >= 0) ob[(size_t)nid * DIM + col] = acc[n];
    }
}

// ======================= K2: per-edge attention logits (r-sorted) =============
// Block = 32 sorted entries x 8 heads. Entries in a block span <= 2 relation
// types (r-classes are ~67K wide), so only 2 A-slots (16.6 KB LDS) are staged.
// A layout: stride 260 floats per head -> octet lanes (h=0..7) start at banks
// 4h+c: 8 disjoint 4-bank groups per float4 read; octets broadcast. ~0 conflicts.

__global__ __launch_bounds__(256) void k_edge_a2(
    const float* __restrict__ kbuf, const float* __restrict__ qbuf,
    const int* __restrict__ sp_src, const int* __restrict__ sp_dst,
    const int* __restrict__ sp_r, const int* __restrict__ sp_pos,
    const float* __restrict__ rel_att, const float* __restrict__ rel_pri,
    float* __restrict__ a_ws, int nE) {
    __shared__ float A2[2][8 * 260];   // 2 r-slots, 8 heads, 16x16 each (stride 260)
    __shared__ float pri[2][8];
    __shared__ int r01[2];
    int b = blockIdx.x;
    int e0 = b * 32;
    int tid = threadIdx.x;
    int nHere = nE - e0; if (nHere > 32) nHere = 32;
    if (nHere <= 0) return;
    if (tid == 0) { r01[0] = sp_r[e0]; r01[1] = sp_r[e0 + nHere - 1]; }
    __syncthreads();
    int r0 = r01[0], r1 = r01[1];
    for (int idx = tid; idx < 2 * 2048; idx += 256) {
        int slot = idx >> 11;
        if (slot == 1 && r1 == r0) break;      // slot1 unused when uniform
        int rem = idx & 2047;
        int h = rem >> 8, dj = rem & 255;
        int rr = slot ? r1 : r0;
        A2[slot][h * 260 + dj] = rel_att[(h * R_TYPES + rr) * 256 + dj];
    }
    if (tid < 16) {
        int slot = tid >> 3, h = tid & 7;
        pri[slot][h] = rel_pri[h * R_TYPES + (slot ? r1 : r0)] * 0.25f;
    }
    __syncthreads();
    int el = tid >> 3;      // entry 0..31
    int h  = tid & 7;
    int q2 = e0 + el;
    if (q2 >= nE) return;
    int s = sp_src[q2], dn = sp_dst[q2], r = sp_r[q2];
    int slot = (r == r0) ? 0 : 1;
    const float4* kp = (const float4*)(kbuf + (size_t)s  * DIM + h * 16);
    const float4* qp = (const float4*)(qbuf + (size_t)dn * DIM + h * 16);
    float4 k4[4], q4[4];
#pragma unroll
    for (int i = 0; i < 4; ++i) { k4[i] = kp[i]; q4[i] = qp[i]; }
    float kk[16] = {k4[0].x,k4[0].y,k4[0].z,k4[0].w, k4[1].x,k4[1].y,k4[1].z,k4[1].w,
                    k4[2].x,k4[2].y,k4[2].z,k4[2].w, k4[3].x,k4[3].y,k4[3].z,k4[3].w};
    float qq[16] = {q4[0].x,q4[0].y,q4[0].z,q4[0].w, q4[1].x,q4[1].y,q4[1].z,q4[1].w,
                    q4[2].x,q4[2].y,q4[2].z,q4[2].w, q4[3].x,q4[3].y,q4[3].z,q4[3].w};
    const float4* A4 = (const float4*)&A2[slot][h * 260];
    float accj[16];
#pragma unroll
    for (int j = 0; j < 16; ++j) accj[j] = 0.f;
#pragma unroll
    for (int d = 0; d < 16; ++d) {
        float kd = kk[d];
#pragma unroll
        for (int jj = 0; jj < 4; ++jj) {
            float4 a4 = A4[d * 4 + jj];
            accj[jj * 4 + 0] = fmaf(kd, a4.x, accj[jj * 4 + 0]);
            accj[jj * 4 + 1] = fmaf(kd, a4.y, accj[jj * 4 + 1]);
            accj[jj * 4 + 2] = fmaf(kd, a4.z, accj[jj * 4 + 2]);
            accj[jj * 4 + 3] = fmaf(kd, a4.w, accj[jj * 4 + 3]);
        }
    }
    float acc = 0.f;
#pragma unroll
    for (int j = 0; j < 16; ++j) acc = fmaf(accj[j], qq[j], acc);
    a_ws[(size_t)sp_pos[q2] * 8 + h] = acc * pri[slot][h];
}

// ======================= K3: per-node softmax + aggregation ===================
// All edge metadata (a, src, etype) now read sequentially by CSR position.

__global__ void k_aggregate2(const float* __restrict__ vbuf, const float* __restrict__ a_ws,
                             const int* __restrict__ offs_end, const int* __restrict__ deg,
                             const int* __restrict__ esrc_s, const int* __restrict__ ety_s,
                             const float* __restrict__ rel_msg,
                             float* __restrict__ hacc, int n) {
    __shared__ float wsum[4][R_TYPES * 4 * 16];
    int wid = threadIdx.x >> 6;
    int lane = threadIdx.x & 63;
    int node = blockIdx.x * 4 + wid;
    bool valid = node < n;
    int g = lane >> 4;
    int d = lane & 15;
    int end = valid ? offs_end[node] : 0;
    int dg  = valid ? deg[node] : 0;
    int start = end - dg;
    float* ws_w = wsum[wid];

    for (int ho = 0; ho < 2; ++ho) {
        int h = ho * 4 + g;
        for (int r = 0; r < R_TYPES; ++r) ws_w[r * 64 + g * 16 + d] = 0.f;
        float m = -1e30f;
        for (int p = start; p < end; ++p)
            m = fmaxf(m, a_ws[(size_t)p * 8 + h]);
        float den = 0.f;
        for (int p = start; p < end; ++p) {
            float ex = __expf(a_ws[(size_t)p * 8 + h] - m);
            den += ex;
            int s = esrc_s[p], r = ety_s[p];
            float vv = vbuf[(size_t)s * DIM + h * D_HEAD + d];
            ws_w[r * 64 + g * 16 + d] += ex * vv;
        }
        __syncthreads();
        float acc = 0.f;
        for (int r = 0; r < R_TYPES; ++r) {
            const float* M = rel_msg + ((size_t)h * R_TYPES + r) * 256;
#pragma unroll
            for (int dp = 0; dp < 16; ++dp)
                acc = fmaf(ws_w[r * 64 + g * 16 + dp], M[dp * 16 + d], acc);
        }
        if (valid)
            hacc[(size_t)node * DIM + h * D_HEAD + d] = acc / fmaxf(den, 1e-9f);
        __syncthreads();
    }
}

// ======================= K4: tiled Wa + gate + residual + LayerNorm ===========

__global__ __launch_bounds__(256) void k_final_gemm(
    const float* __restrict__ x, const int* __restrict__ nlist,
    const int* __restrict__ tile_type, const int* __restrict__ ntiles_g,
    const float* __restrict__ Wa, const float* __restrict__ skip,
    const float* __restrict__ gamma, const float* __restrict__ beta,
    float* __restrict__ out) {
    __shared__ float hs[BN][DIM];
    __shared__ float ys[BN][DIM];
    __shared__ int sids[BN];
    __shared__ float mred[BN], ired[BN];
    int b = blockIdx.x;
    if (b >= *ntiles_g) return;
    int tid = threadIdx.x;
    if (tid < BN) sids[tid] = nlist[b * BN + tid];
    __syncthreads();
    for (int idx = tid; idx < BN * DIM; idx += 256) {
        int row = idx >> 7, col = idx & 127;
        int nid = sids[row];
        hs[row][col] = (nid >= 0) ? out[(size_t)nid * DIM + col] : 0.f;
    }
    __syncthreads();
    int t = tile_type[b];
    int half = tid >> 7, col = tid & 127;
    const float* W = Wa + (size_t)t * DIM * DIM;
    float acc[8];
#pragma unroll
    for (int n = 0; n < 8; ++n) acc[n] = 0.f;
#pragma unroll 4
    for (int d = 0; d < DIM; ++d) {
        float w = W[d * DIM + col];
#pragma unroll
        for (int n = 0; n < 8; ++n) acc[n] = fmaf(hs[half * 8 + n][d], w, acc[n]);
    }
    float gte = 1.f / (1.f + __expf(-skip[t]));
#pragma unroll
    for (int n = 0; n < 8; ++n) {
        int row = half * 8 + n;
        int nid = sids[row];
        float xv = (nid >= 0) ? x[(size_t)nid * DIM + col] : 0.f;
        ys[row][col] = xv * (2.f - gte) + acc[n] * gte;
    }
    __syncthreads();
    int ng = tid >> 4, l16 = tid & 15;
    float s = 0.f, s2 = 0.f;
#pragma unroll
    for (int k2 = 0; k2 < 8; ++k2) {
        float yv = ys[ng][l16 + 16 * k2];
        s += yv; s2 += yv * yv;
    }
#pragma unroll
    for (int m = 1; m < 16; m <<= 1) {
        s  += __shfl_xor(s, m, 64);
        s2 += __shfl_xor(s2, m, 64);
    }
    if (l16 == 0) {
        float mu = s * (1.f / DIM);
        float var = s2 * (1.f / DIM) - mu * mu;
        mred[ng] = mu;
        ired[ng] = rsqrtf(var + 1e-5f);
    }
    __syncthreads();
    float gm = gamma[col], bt = beta[col];
#pragma unroll
    for (int n = 0; n < 8; ++n) {
        int row = half * 8 + n;
        int nid = sids[row];
        if (nid >= 0)
            out[(size_t)nid * DIM + col] = (ys[row][col] - mred[row]) * ired[row] * gm + bt;
    }
}

// ======================= launcher =======================

extern "C" void kernel_launch(void* const* d_in, const int* in_sizes, int n_in,
                              void* d_out, int out_size, void* d_ws, size_t ws_size,
                              hipStream_t stream) {
    const float* x       = (const float*)d_in[0];
    const int*   src     = (const int*)d_in[1];
    const int*   dst     = (const int*)d_in[2];
    const int*   ntype   = (const int*)d_in[3];
    const int*   etype   = (const int*)d_in[4];
    const float* Wk      = (const float*)d_in[5];
    const float* Wq      = (const float*)d_in[6];
    const float* Wv      = (const float*)d_in[7];
    const float* Wa      = (const float*)d_in[8];
    const float* rel_pri = (const float*)d_in[9];
    const float* rel_att = (const float*)d_in[10];
    const float* rel_msg = (const float*)d_in[11];
    const float* skip    = (const float*)d_in[12];
    const float* gamma   = (const float*)d_in[13];
    const float* beta    = (const float*)d_in[14];
    float* out = (float*)d_out;

    const int N = N_NODES, E = N_EDGES;

    // workspace layout
    char* ws = (char*)d_ws;
    float* kb   = (float*)ws;                          // N*128
    float* qb   = kb + (size_t)N * DIM;                // N*128
    float* vb   = qb + (size_t)N * DIM;                // N*128
    float* a_ws = vb + (size_t)N * DIM;                // E*8
    int* deg     = (int*)(a_ws + (size_t)E * H_HEADS); // N
    int* offs    = deg + N;                            // N
    int* esrc_s  = offs + N;                           // E
    int* edst_s  = esrc_s + E;                         // E
    int* ety_s   = edst_s + E;                         // E
    int* sp_src  = ety_s + E;                          // E
    int* sp_dst  = sp_src + E;                         // E
    int* sp_r    = sp_dst + E;                         // E
    int* sp_pos  = sp_r + E;                           // E
    int* rhist   = sp_pos + E;                         // R_TYPES*NBLK_E
    int* partial = rhist + R_TYPES * NBLK_E;           // 256
    int* tcnt    = partial + 256;                      // 4
    int* pbase   = tcnt + T_TYPES;                     // 4
    int* ntiles  = pbase + T_TYPES;                    // 1
    int* tile_type = ntiles + 1;                       // MAX_TILES
    int* nlist   = tile_type + MAX_TILES;              // MAX_TILES*BN
    int* wpos    = nlist + (size_t)MAX_TILES * BN;     // N

    const int nbScan = (N + 255) / 256;

    // CSR build (edges by dst), materializing sorted src/dst/etype
    hipMemsetAsync(deg, 0, (size_t)N * sizeof(int), stream);
    k_count<<<(E + 255) / 256, 256, 0, stream>>>(dst, deg, E);
    k_scanA<<<nbScan, 256, 0, stream>>>(deg, offs, partial, N);
    k_scanB<<<1, 256, 0, stream>>>(partial, nbScan);
    k_scanC<<<nbScan, 256, 0, stream>>>(offs, partial, N);
    k_scatter2<<<(E + 255) / 256, 256, 0, stream>>>(
        src, dst, etype, offs, esrc_s, edst_s, ety_s, E);

    // counting-sort CSR positions by relation type
    k_rhist<<<NBLK_E, 256, 0, stream>>>(ety_s, rhist, E);
    k_rscan<<<1, 256, 0, stream>>>(rhist, R_TYPES * NBLK_E);
    k_rscatter<<<NBLK_E, 256, 0, stream>>>(
        esrc_s, edst_s, ety_s, rhist, sp_src, sp_dst, sp_r, sp_pos, E);

    // node type buckets (padded 16-node tiles)
    hipMemsetAsync(tcnt, 0, T_TYPES * sizeof(int), stream);
    k_tcount_agg<<<nbScan, 256, 0, stream>>>(ntype, tcnt, wpos, N);
    k_tsetup<<<1, 256, 0, stream>>>(tcnt, pbase, ntiles, tile_type);
    hipMemsetAsync(nlist, 0xFF, (size_t)MAX_TILES * BN * sizeof(int), stream);
    k_tscatter2<<<nbScan, 256, 0, stream>>>(ntype, wpos, pbase, nlist, N);

    // projections (tiled per-type GEMM)
    k_kqv_gemm<<<MAX_TILES, 384, 0, stream>>>(
        x, nlist, tile_type, ntiles, Wk, Wq, Wv, kb, qb, vb);

    // edge logits (r-sorted, conflict-free LDS, high occupancy)
    k_edge_a2<<<(E + 31) / 32, 256, 0, stream>>>(
        kb, qb, sp_src, sp_dst, sp_r, sp_pos, rel_att, rel_pri, a_ws, E);

    // per-node softmax + message aggregation -> d_out (scratch)
    k_aggregate2<<<(N + 3) / 4, 256, 0, stream>>>(
        vb, a_ws, offs, deg, esrc_s, ety_s, rel_msg, out, N);

    // output projection + gate + residual + LayerNorm (in place on d_out)
    k_final_gemm<<<MAX_TILES, 256, 0, stream>>>(
        x, nlist, tile_type, ntiles, Wa, skip, gamma, beta, out);
}

// Round 5
// 474.008 us; speedup vs baseline: 2.5892x; 1.0989x over previous
//
#include <hip/hip_runtime.h>
#include <math.h>

#define N_NODES 50000
#define N_EDGES 400000
#define H_HEADS 8
#define D_HEAD 16
#define R_TYPES 6
#define T_TYPES 4
#define DIM 128
#define BN 16                                      // nodes per GEMM tile
#define MAX_TILES ((N_NODES + BN - 1) / BN + T_TYPES)
#define NBLK_E ((N_EDGES + 255) / 256)             // 1563

// ======================= CSR build (group edges by dst) =======================

__global__ void k_count(const int* __restrict__ dst, int* __restrict__ deg, int n) {
    int e = blockIdx.x * blockDim.x + threadIdx.x;
    if (e < n) atomicAdd(&deg[dst[e]], 1);
}

__global__ void k_scanA(const int* __restrict__ deg, int* __restrict__ offs,
                        int* __restrict__ partial, int n) {
    __shared__ int tmp[256];
    int tid = threadIdx.x;
    int i = blockIdx.x * 256 + tid;
    int v = (i < n) ? deg[i] : 0;
    tmp[tid] = v;
    __syncthreads();
    for (int o = 1; o < 256; o <<= 1) {
        int t = (tid >= o) ? tmp[tid - o] : 0;
        __syncthreads();
        tmp[tid] += t;
        __syncthreads();
    }
    if (i < n) offs[i] = tmp[tid] - v;
    if (tid == 255) partial[blockIdx.x] = tmp[255];
}

__global__ void k_scanB(int* __restrict__ partial, int nb) {
    __shared__ int tmp[256];
    int tid = threadIdx.x;
    int v = (tid < nb) ? partial[tid] : 0;
    tmp[tid] = v;
    __syncthreads();
    for (int o = 1; o < 256; o <<= 1) {
        int t = (tid >= o) ? tmp[tid - o] : 0;
        __syncthreads();
        tmp[tid] += t;
        __syncthreads();
    }
    if (tid < nb) partial[tid] = tmp[tid] - v;
}

__global__ void k_scanC(int* __restrict__ offs, const int* __restrict__ partial, int n) {
    int i = blockIdx.x * 256 + threadIdx.x;
    if (i < n) offs[i] += partial[blockIdx.x];
}

// scatter edges into CSR order, materializing src/dst/etype at sorted position
__global__ void k_scatter2(const int* __restrict__ src, const int* __restrict__ dst,
                           const int* __restrict__ etype, int* __restrict__ offs,
                           int* __restrict__ esrc_s, int* __restrict__ edst_s,
                           int* __restrict__ ety_s, int n) {
    int e = blockIdx.x * blockDim.x + threadIdx.x;
    if (e < n) {
        int pos = atomicAdd(&offs[dst[e]], 1);   // offs becomes END offset
        esrc_s[pos] = src[e];
        edst_s[pos] = dst[e];
        ety_s[pos]  = etype[e];
    }
}

// ======================= r-sort of CSR positions (counting sort) ==============

__global__ void k_rhist(const int* __restrict__ ety_s, int* __restrict__ rcnt, int n) {
    __shared__ int h[R_TYPES];
    int tid = threadIdx.x;
    if (tid < R_TYPES) h[tid] = 0;
    __syncthreads();
    int i = blockIdx.x * 256 + tid;
    if (i < n) atomicAdd(&h[ety_s[i]], 1);
    __syncthreads();
    if (tid < R_TYPES) rcnt[tid * NBLK_E + blockIdx.x] = h[tid];
}

__global__ void k_rscan(int* __restrict__ a, int total) {
    __shared__ int tmp[256];
    __shared__ int carry_s;
    int tid = threadIdx.x;
    if (tid == 0) carry_s = 0;
    __syncthreads();
    for (int base = 0; base < total; base += 256) {
        int i = base + tid;
        int v = (i < total) ? a[i] : 0;
        tmp[tid] = v;
        __syncthreads();
        for (int o = 1; o < 256; o <<= 1) {
            int t = (tid >= o) ? tmp[tid - o] : 0;
            __syncthreads();
            tmp[tid] += t;
            __syncthreads();
        }
        int carry = carry_s;
        if (i < total) a[i] = carry + tmp[tid] - v;   // exclusive
        __syncthreads();
        if (tid == 255) carry_s = carry + tmp[255];
        __syncthreads();
    }
}

__global__ void k_rscatter(const int* __restrict__ esrc_s, const int* __restrict__ edst_s,
                           const int* __restrict__ ety_s, const int* __restrict__ rbase,
                           int* __restrict__ sp_src, int* __restrict__ sp_dst,
                           int* __restrict__ sp_r, int* __restrict__ sp_pos, int n) {
    __shared__ int hist[R_TYPES];
    __shared__ int base[R_TYPES];
    int tid = threadIdx.x;
    if (tid < R_TYPES) hist[tid] = 0;
    __syncthreads();
    int p = blockIdx.x * 256 + tid;
    int r = 0, rank = 0;
    if (p < n) {
        r = ety_s[p];
        rank = atomicAdd(&hist[r], 1);
    }
    __syncthreads();
    if (tid < R_TYPES) base[tid] = rbase[tid * NBLK_E + blockIdx.x];
    __syncthreads();
    if (p < n) {
        int q2 = base[r] + rank;
        sp_src[q2] = esrc_s[p];
        sp_dst[q2] = edst_s[p];
        sp_r[q2]   = r;
        sp_pos[q2] = p;
    }
}

// ======================= node type bucketing (padded 16-node tiles) ===========

__global__ void k_tcount_agg(const int* __restrict__ ntype, int* __restrict__ tcnt,
                             int* __restrict__ wpos, int n) {
    __shared__ int hist[T_TYPES];
    __shared__ int base[T_TYPES];
    int tid = threadIdx.x;
    if (tid < T_TYPES) hist[tid] = 0;
    __syncthreads();
    int i = blockIdx.x * 256 + tid;
    int t = 0, rank = 0;
    if (i < n) {
        t = ntype[i];
        rank = atomicAdd(&hist[t], 1);
    }
    __syncthreads();
    if (tid < T_TYPES)
        base[tid] = (hist[tid] > 0) ? atomicAdd(&tcnt[tid], hist[tid]) : 0;
    __syncthreads();
    if (i < n) wpos[i] = base[t] + rank;
}

__global__ void k_tsetup(const int* __restrict__ tcnt, int* __restrict__ pbase,
                         int* __restrict__ ntiles_g, int* __restrict__ tile_type) {
    __shared__ int off[T_TYPES + 1];
    if (threadIdx.x == 0) {
        int o = 0;
        for (int t = 0; t < T_TYPES; ++t) {
            off[t] = o;
            pbase[t] = o * BN;
            o += (tcnt[t] + BN - 1) / BN;
        }
        off[T_TYPES] = o;
        *ntiles_g = o;
    }
    __syncthreads();
    int total = off[T_TYPES];
    for (int i = threadIdx.x; i < total; i += blockDim.x) {
        int t = 0;
        while (t < T_TYPES - 1 && i >= off[t + 1]) ++t;
        tile_type[i] = t;
    }
}

__global__ void k_tscatter2(const int* __restrict__ ntype, const int* __restrict__ wpos,
                            const int* __restrict__ pbase, int* __restrict__ nlist, int n) {
    int i = blockIdx.x * 256 + threadIdx.x;
    if (i < n) nlist[pbase[ntype[i]] + wpos[i]] = i;
}

// ======================= K1: tiled typed-linear k,q,v =======================

__global__ __launch_bounds__(384) void k_kqv_gemm(
    const float* __restrict__ x, const int* __restrict__ nlist,
    const int* __restrict__ tile_type, const int* __restrict__ ntiles_g,
    const float* __restrict__ Wk, const float* __restrict__ Wq,
    const float* __restrict__ Wv,
    float* __restrict__ kb, float* __restrict__ qb, float* __restrict__ vb) {
    __shared__ float xs[BN][DIM];
    __shared__ int sids[BN];
    int b = blockIdx.x;
    if (b >= *ntiles_g) return;
    int tid = threadIdx.x;
    if (tid < BN) sids[tid] = nlist[b * BN + tid];
    __syncthreads();
    for (int idx = tid; idx < BN * DIM; idx += 384) {
        int row = idx >> 7, col = idx & 127;
        int nid = sids[row];
        xs[row][col] = (nid >= 0) ? x[(size_t)nid * DIM + col] : 0.f;
    }
    __syncthreads();
    int t = tile_type[b];
    int mat = tid >> 7;          // 0=k 1=q 2=v
    int col = tid & 127;
    const float* W = (mat == 0 ? Wk : (mat == 1 ? Wq : Wv)) + (size_t)t * DIM * DIM;
    float acc[BN];
#pragma unroll
    for (int n = 0; n < BN; ++n) acc[n] = 0.f;
#pragma unroll 4
    for (int d = 0; d < DIM; ++d) {
        float w = W[d * DIM + col];
#pragma unroll
        for (int n = 0; n < BN; ++n) acc[n] = fmaf(xs[n][d], w, acc[n]);
    }
    float* ob = (mat == 0 ? kb : (mat == 1 ? qb : vb));
    for (int n = 0; n < BN; ++n) {
        int nid = sids[n];
        if (nid >= 0) ob[(size_t)nid * DIM + col] = acc[n];
    }
}

// ======================= K2: per-edge attention logits (r-sorted) =============

__global__ __launch_bounds__(256) void k_edge_a2(
    const float* __restrict__ kbuf, const float* __restrict__ qbuf,
    const int* __restrict__ sp_src, const int* __restrict__ sp_dst,
    const int* __restrict__ sp_r, const int* __restrict__ sp_pos,
    const float* __restrict__ rel_att, const float* __restrict__ rel_pri,
    float* __restrict__ a_ws, int nE) {
    __shared__ float A2[2][8 * 260];   // 2 r-slots, 8 heads, 16x16 each (stride 260)
    __shared__ float pri[2][8];
    __shared__ int r01[2];
    int b = blockIdx.x;
    int e0 = b * 32;
    int tid = threadIdx.x;
    int nHere = nE - e0; if (nHere > 32) nHere = 32;
    if (nHere <= 0) return;
    if (tid == 0) { r01[0] = sp_r[e0]; r01[1] = sp_r[e0 + nHere - 1]; }
    __syncthreads();
    int r0 = r01[0], r1 = r01[1];
    for (int idx = tid; idx < 2 * 2048; idx += 256) {
        int slot = idx >> 11;
        if (slot == 1 && r1 == r0) break;      // slot1 unused when uniform
        int rem = idx & 2047;
        int h = rem >> 8, dj = rem & 255;
        int rr = slot ? r1 : r0;
        A2[slot][h * 260 + dj] = rel_att[(h * R_TYPES + rr) * 256 + dj];
    }
    if (tid < 16) {
        int slot = tid >> 3, h = tid & 7;
        pri[slot][h] = rel_pri[h * R_TYPES + (slot ? r1 : r0)] * 0.25f;
    }
    __syncthreads();
    int el = tid >> 3;      // entry 0..31
    int h  = tid & 7;
    int q2 = e0 + el;
    if (q2 >= nE) return;
    int s = sp_src[q2], dn = sp_dst[q2], r = sp_r[q2];
    int slot = (r == r0) ? 0 : 1;
    const float4* kp = (const float4*)(kbuf + (size_t)s  * DIM + h * 16);
    const float4* qp = (const float4*)(qbuf + (size_t)dn * DIM + h * 16);
    float4 k4[4], q4[4];
#pragma unroll
    for (int i = 0; i < 4; ++i) { k4[i] = kp[i]; q4[i] = qp[i]; }
    float kk[16] = {k4[0].x,k4[0].y,k4[0].z,k4[0].w, k4[1].x,k4[1].y,k4[1].z,k4[1].w,
                    k4[2].x,k4[2].y,k4[2].z,k4[2].w, k4[3].x,k4[3].y,k4[3].z,k4[3].w};
    float qq[16] = {q4[0].x,q4[0].y,q4[0].z,q4[0].w, q4[1].x,q4[1].y,q4[1].z,q4[1].w,
                    q4[2].x,q4[2].y,q4[2].z,q4[2].w, q4[3].x,q4[3].y,q4[3].z,q4[3].w};
    const float4* A4 = (const float4*)&A2[slot][h * 260];
    float accj[16];
#pragma unroll
    for (int j = 0; j < 16; ++j) accj[j] = 0.f;
#pragma unroll
    for (int d = 0; d < 16; ++d) {
        float kd = kk[d];
#pragma unroll
        for (int jj = 0; jj < 4; ++jj) {
            float4 a4 = A4[d * 4 + jj];
            accj[jj * 4 + 0] = fmaf(kd, a4.x, accj[jj * 4 + 0]);
            accj[jj * 4 + 1] = fmaf(kd, a4.y, accj[jj * 4 + 1]);
            accj[jj * 4 + 2] = fmaf(kd, a4.z, accj[jj * 4 + 2]);
            accj[jj * 4 + 3] = fmaf(kd, a4.w, accj[jj * 4 + 3]);
        }
    }
    float acc = 0.f;
#pragma unroll
    for (int j = 0; j < 16; ++j) acc = fmaf(accj[j], qq[j], acc);
    a_ws[(size_t)sp_pos[q2] * 8 + h] = acc * pri[slot][h];
}

// ======================= K3: per-node softmax + aggregation ===================
// 128 threads per node (all 8 heads at once), 2 nodes per 256-block.
// Max pass parallelized across d-lanes; exp-weighted v accumulated into per-r
// REGISTER buckets (6-way select) -> one LDS write -> rel_msg matmul epilogue.

__global__ __launch_bounds__(256) void k_aggregate3(
    const float* __restrict__ vbuf, const float* __restrict__ a_ws,
    const int* __restrict__ offs_end, const int* __restrict__ deg,
    const int* __restrict__ esrc_s, const int* __restrict__ ety_s,
    const float* __restrict__ rel_msg,
    float* __restrict__ hacc, int n) {
    __shared__ float wsum[2][R_TYPES * 128];   // 6 KB
    int tid = threadIdx.x;
    int nb = tid >> 7;
    int lane2 = tid & 127;
    int node = blockIdx.x * 2 + nb;
    bool valid = node < n;
    int h = lane2 >> 4;
    int d = lane2 & 15;
    int end = valid ? offs_end[node] : 0;
    int dg  = valid ? deg[node] : 0;
    int start = end - dg;

    // pass 1: parallel max (d-lanes split edges; coalesced 512B per 16-edge chunk)
    float mmax = -1e30f;
    for (int p = start + d; p < end; p += 16)
        mmax = fmaxf(mmax, a_ws[(size_t)p * 8 + h]);
#pragma unroll
    for (int mask = 1; mask < 16; mask <<= 1)
        mmax = fmaxf(mmax, __shfl_xor(mmax, mask, 64));

    // pass 2: exp-weighted accumulation into per-r register buckets
    float accR[R_TYPES] = {0.f, 0.f, 0.f, 0.f, 0.f, 0.f};
    float den = 0.f;
#pragma unroll 2
    for (int p = start; p < end; ++p) {
        float av = a_ws[(size_t)p * 8 + h];     // broadcast within h-group
        float ex = __expf(av - mmax);
        den += ex;
        int s = esrc_s[p];
        int r = ety_s[p];
        float exvv = ex * vbuf[(size_t)s * DIM + lane2];   // coalesced 512B row
#pragma unroll
        for (int rr = 0; rr < R_TYPES; ++rr)
            accR[rr] += (rr == r) ? exvv : 0.f;
    }

    float* wsn = &wsum[nb][0];
#pragma unroll
    for (int rr = 0; rr < R_TYPES; ++rr)
        wsn[rr * 128 + lane2] = accR[rr];
    __syncthreads();

    // epilogue: out[h][d] = (1/den) * sum_r sum_dp bucket[r][h][dp] * M[h][r][dp][d]
    float acc = 0.f;
#pragma unroll
    for (int rr = 0; rr < R_TYPES; ++rr) {
        const float* M = rel_msg + ((size_t)h * R_TYPES + rr) * 256;
#pragma unroll
        for (int dp = 0; dp < 16; ++dp)
            acc = fmaf(wsn[rr * 128 + h * 16 + dp], M[dp * 16 + d], acc);
    }
    if (valid)
        hacc[(size_t)node * DIM + lane2] = acc / fmaxf(den, 1e-9f);
}

// ======================= K4: tiled Wa + gate + residual + LayerNorm ===========

__global__ __launch_bounds__(256) void k_final_gemm(
    const float* __restrict__ x, const int* __restrict__ nlist,
    const int* __restrict__ tile_type, const int* __restrict__ ntiles_g,
    const float* __restrict__ Wa, const float* __restrict__ skip,
    const float* __restrict__ gamma, const float* __restrict__ beta,
    float* __restrict__ out) {
    __shared__ float hs[BN][DIM];
    __shared__ float ys[BN][DIM];
    __shared__ int sids[BN];
    __shared__ float mred[BN], ired[BN];
    int b = blockIdx.x;
    if (b >= *ntiles_g) return;
    int tid = threadIdx.x;
    if (tid < BN) sids[tid] = nlist[b * BN + tid];
    __syncthreads();
    for (int idx = tid; idx < BN * DIM; idx += 256) {
        int row = idx >> 7, col = idx & 127;
        int nid = sids[row];
        hs[row][col] = (nid >= 0) ? out[(size_t)nid * DIM + col] : 0.f;
    }
    __syncthreads();
    int t = tile_type[b];
    int half = tid >> 7, col = tid & 127;
    const float* W = Wa + (size_t)t * DIM * DIM;
    float acc[8];
#pragma unroll
    for (int n = 0; n < 8; ++n) acc[n] = 0.f;
#pragma unroll 4
    for (int d = 0; d < DIM; ++d) {
        float w = W[d * DIM + col];
#pragma unroll
        for (int n = 0; n < 8; ++n) acc[n] = fmaf(hs[half * 8 + n][d], w, acc[n]);
    }
    float gte = 1.f / (1.f + __expf(-skip[t]));
#pragma unroll
    for (int n = 0; n < 8; ++n) {
        int row = half * 8 + n;
        int nid = sids[row];
        float xv = (nid >= 0) ? x[(size_t)nid * DIM + col] : 0.f;
        ys[row][col] = xv * (2.f - gte) + acc[n] * gte;
    }
    __syncthreads();
    int ng = tid >> 4, l16 = tid & 15;
    float s = 0.f, s2 = 0.f;
#pragma unroll
    for (int k2 = 0; k2 < 8; ++k2) {
        float yv = ys[ng][l16 + 16 * k2];
        s += yv; s2 += yv * yv;
    }
#pragma unroll
    for (int m = 1; m < 16; m <<= 1) {
        s  += __shfl_xor(s, m, 64);
        s2 += __shfl_xor(s2, m, 64);
    }
    if (l16 == 0) {
        float mu = s * (1.f / DIM);
        float var = s2 * (1.f / DIM) - mu * mu;
        mred[ng] = mu;
        ired[ng] = rsqrtf(var + 1e-5f);
    }
    __syncthreads();
    float gm = gamma[col], bt = beta[col];
#pragma unroll
    for (int n = 0; n < 8; ++n) {
        int row = half * 8 + n;
        int nid = sids[row];
        if (nid >= 0)
            out[(size_t)nid * DIM + col] = (ys[row][col] - mred[row]) * ired[row] * gm + bt;
    }
}

// ======================= launcher =======================

extern "C" void kernel_launch(void* const* d_in, const int* in_sizes, int n_in,
                              void* d_out, int out_size, void* d_ws, size_t ws_size,
                              hipStream_t stream) {
    const float* x       = (const float*)d_in[0];
    const int*   src     = (const int*)d_in[1];
    const int*   dst     = (const int*)d_in[2];
    const int*   ntype   = (const int*)d_in[3];
    const int*   etype   = (const int*)d_in[4];
    const float* Wk      = (const float*)d_in[5];
    const float* Wq      = (const float*)d_in[6];
    const float* Wv      = (const float*)d_in[7];
    const float* Wa      = (const float*)d_in[8];
    const float* rel_pri = (const float*)d_in[9];
    const float* rel_att = (const float*)d_in[10];
    const float* rel_msg = (const float*)d_in[11];
    const float* skip    = (const float*)d_in[12];
    const float* gamma   = (const float*)d_in[13];
    const float* beta    = (const float*)d_in[14];
    float* out = (float*)d_out;

    const int N = N_NODES, E = N_EDGES;

    // workspace layout
    char* ws = (char*)d_ws;
    float* kb   = (float*)ws;                          // N*128
    float* qb   = kb + (size_t)N * DIM;                // N*128
    float* vb   = qb + (size_t)N * DIM;                // N*128
    float* a_ws = vb + (size_t)N * DIM;                // E*8
    int* deg     = (int*)(a_ws + (size_t)E * H_HEADS); // N
    int* offs    = deg + N;                            // N
    int* esrc_s  = offs + N;                           // E
    int* edst_s  = esrc_s + E;                         // E
    int* ety_s   = edst_s + E;                         // E
    int* sp_src  = ety_s + E;                          // E
    int* sp_dst  = sp_src + E;                         // E
    int* sp_r    = sp_dst + E;                         // E
    int* sp_pos  = sp_r + E;                           // E
    int* rhist   = sp_pos + E;                         // R_TYPES*NBLK_E
    int* partial = rhist + R_TYPES * NBLK_E;           // 256
    int* tcnt    = partial + 256;                      // 4
    int* pbase   = tcnt + T_TYPES;                     // 4
    int* ntiles  = pbase + T_TYPES;                    // 1
    int* tile_type = ntiles + 1;                       // MAX_TILES
    int* nlist   = tile_type + MAX_TILES;              // MAX_TILES*BN
    int* wpos    = nlist + (size_t)MAX_TILES * BN;     // N

    const int nbScan = (N + 255) / 256;

    // CSR build (edges by dst), materializing sorted src/dst/etype
    hipMemsetAsync(deg, 0, (size_t)N * sizeof(int), stream);
    k_count<<<(E + 255) / 256, 256, 0, stream>>>(dst, deg, E);
    k_scanA<<<nbScan, 256, 0, stream>>>(deg, offs, partial, N);
    k_scanB<<<1, 256, 0, stream>>>(partial, nbScan);
    k_scanC<<<nbScan, 256, 0, stream>>>(offs, partial, N);
    k_scatter2<<<(E + 255) / 256, 256, 0, stream>>>(
        src, dst, etype, offs, esrc_s, edst_s, ety_s, E);

    // counting-sort CSR positions by relation type
    k_rhist<<<NBLK_E, 256, 0, stream>>>(ety_s, rhist, E);
    k_rscan<<<1, 256, 0, stream>>>(rhist, R_TYPES * NBLK_E);
    k_rscatter<<<NBLK_E, 256, 0, stream>>>(
        esrc_s, edst_s, ety_s, rhist, sp_src, sp_dst, sp_r, sp_pos, E);

    // node type buckets (padded 16-node tiles)
    hipMemsetAsync(tcnt, 0, T_TYPES * sizeof(int), stream);
    k_tcount_agg<<<nbScan, 256, 0, stream>>>(ntype, tcnt, wpos, N);
    k_tsetup<<<1, 256, 0, stream>>>(tcnt, pbase, ntiles, tile_type);
    hipMemsetAsync(nlist, 0xFF, (size_t)MAX_TILES * BN * sizeof(int), stream);
    k_tscatter2<<<nbScan, 256, 0, stream>>>(ntype, wpos, pbase, nlist, N);

    // projections (tiled per-type GEMM)
    k_kqv_gemm<<<MAX_TILES, 384, 0, stream>>>(
        x, nlist, tile_type, ntiles, Wk, Wq, Wv, kb, qb, vb);

    // edge logits (r-sorted, conflict-free LDS)
    k_edge_a2<<<(E + 31) / 32, 256, 0, stream>>>(
        kb, qb, sp_src, sp_dst, sp_r, sp_pos, rel_att, rel_pri, a_ws, E);

    // per-node softmax + message aggregation -> d_out (scratch)
    k_aggregate3<<<(N + 1) / 2, 256, 0, stream>>>(
        vb, a_ws, offs, deg, esrc_s, ety_s, rel_msg, out, N);

    // output projection + gate + residual + LayerNorm (in place on d_out)
    k_final_gemm<<<MAX_TILES, 256, 0, stream>>>(
        x, nlist, tile_type, ntiles, Wa, skip, gamma, beta, out);
}